// Round 9
// baseline (22333.266 us; speedup 1.0000x reference)
//
#include <hip/hip_runtime.h>

#define MDIM 512
#define NDIM 1024
#define MAX_OUTER 200
#define X_INNER 20
#define RHO 1.0f
#define XSTEP 1e-3f

#define GBLK 32
#define TPB 256
#define NPER (NDIM / GBLK) /* 32 x-rows per block */
#define MPER (MDIM / GBLK) /* 16 s/u-rows per block */

__device__ __forceinline__ float wave_reduce_sum(float v) {
#pragma unroll
  for (int off = 32; off > 0; off >>= 1) v += __shfl_xor(v, off, 64);
  return v;
}

// Round-3-exact grid barrier (best measured variant) + block-wide acquire
// fence so PLAIN loads after the barrier are coherent:
//  - writer side: plain stores -> __syncthreads (each wave vmcnt-drains to
//    L2) -> tid0 RELEASE flag store (emits buffer_wbl2: flushes ALL dirty
//    L2 lines, incl. other waves' x/s/u stores, then writes flag to LLC)
//  - reader side: ACQUIRE polls (tid<32, 128B-spread flags, s_sleep(2))
//    -> __syncthreads -> fence(acquire, agent) by ALL threads (buffer_inv:
//    invalidates L1/L2 so plain vector loads refetch from LLC)
__device__ __forceinline__ void grid_barrier(int* flags, int epoch, int bid) {
  __syncthreads();
  if (threadIdx.x == 0)
    __hip_atomic_store(&flags[bid * 32], epoch, __ATOMIC_RELEASE,
                       __HIP_MEMORY_SCOPE_AGENT);
  if (threadIdx.x < GBLK) {
    while (__hip_atomic_load(&flags[threadIdx.x * 32], __ATOMIC_ACQUIRE,
                             __HIP_MEMORY_SCOPE_AGENT) < epoch)
      __builtin_amdgcn_s_sleep(2);
  }
  __syncthreads();
  __builtin_amdgcn_fence(__ATOMIC_ACQUIRE, "agent");
}

// ---------------- kernel 1: M = A^T A  (1024x1024 f32) ----------------

#define ATA_BK 32
#define ATA_BT 64

__global__ void __launch_bounds__(256) ata_kernel(const float* __restrict__ A,
                                                  float* __restrict__ Mout) {
  __shared__ float As[ATA_BK][ATA_BT];
  __shared__ float Bs[ATA_BK][ATA_BT];
  const int bi = blockIdx.y * ATA_BT;
  const int bj = blockIdx.x * ATA_BT;
  const int tid = threadIdx.x;
  const int tx = tid & 15, ty = tid >> 4;
  float acc[4][4] = {};
  for (int k0 = 0; k0 < MDIM; k0 += ATA_BK) {
#pragma unroll
    for (int t = tid; t < ATA_BK * ATA_BT; t += 256) {
      int kk = t >> 6, ii = t & 63;
      As[kk][ii] = A[(size_t)(k0 + kk) * NDIM + bi + ii];
      Bs[kk][ii] = A[(size_t)(k0 + kk) * NDIM + bj + ii];
    }
    __syncthreads();
#pragma unroll
    for (int kk = 0; kk < ATA_BK; ++kk) {
      float a[4], bb[4];
#pragma unroll
      for (int r = 0; r < 4; ++r) a[r] = As[kk][ty * 4 + r];
#pragma unroll
      for (int r = 0; r < 4; ++r) bb[r] = Bs[kk][tx * 4 + r];
#pragma unroll
      for (int r = 0; r < 4; ++r)
#pragma unroll
        for (int q = 0; q < 4; ++q) acc[r][q] = fmaf(a[r], bb[q], acc[r][q]);
    }
    __syncthreads();
  }
#pragma unroll
  for (int r = 0; r < 4; ++r)
#pragma unroll
    for (int q = 0; q < 4; ++q)
      Mout[(size_t)(bi + ty * 4 + r) * NDIM + bj + tx * 4 + q] = acc[r][q];
}

// ---------------- kernel 2: persistent ADMM loop ----------------
// 32 blocks (1 CU each). Block owns 32 x-rows and 16 s/u-rows. All
// cross-block data moves via PLAIN vector ops; coherence comes from the
// barrier's wbl2/inv pair. 21 barriers per outer (20 inner + 1 outer).

__global__ void __launch_bounds__(TPB) admm_kernel(
    const float* __restrict__ A, const float* __restrict__ bvec,
    const float* __restrict__ cvec, const float* __restrict__ Mm,
    float* __restrict__ xg0, float* __restrict__ xg1, float* __restrict__ sg,
    float* __restrict__ ug, int* flags, float* __restrict__ out) {
  __shared__ float4 Ml4[NPER][NDIM / 4];  // 128 KB: block's 32 M-rows
  __shared__ float rs[MDIM];              // r = s + b - u (also u for nu)
  __shared__ float bl[MDIM];              // b cached
  __shared__ float sown[MPER];            // own s slice (persistent)
  __shared__ float uown[MPER];            // own u slice (persistent)
  __shared__ float wl[NPER];              // block's slice of w = A^T r
  __shared__ float cl[NPER];              // block's slice of c
  __shared__ float wred[NPER][9];         // reduction scratch (padded)

  const int tid = threadIdx.x;
  const int bid = blockIdx.x;
  const int wave = tid >> 6;
  const int lane = tid & 63;
  const int i0 = bid * NPER;  // x/w/nu row offset
  const int k0 = bid * MPER;  // s/u/lambda row offset

  // ---- stage M-rows, b, c; zero own s/u ----
  {
    const float4* Msrc = (const float4*)(Mm + (size_t)i0 * NDIM);
    float4* Mdst = &Ml4[0][0];
    for (int f = tid; f < NPER * NDIM / 4; f += TPB) Mdst[f] = Msrc[f];
  }
  if (tid < NPER) cl[tid] = cvec[i0 + tid];
  if (tid < MPER) {
    sown[tid] = 0.0f;
    uown[tid] = 0.0f;
  }
  for (int k = tid; k < MDIM; k += TPB) bl[k] = bvec[k];

  // full x per wave in regs: lane holds float4 x4[64*t + lane], t in 0..3
  float4 xr[4];
#pragma unroll
  for (int t = 0; t < 4; ++t) xr[t] = make_float4(0.f, 0.f, 0.f, 0.f);
  // each lane redundantly tracks the wave's 8 own x values (divergence-free)
  float ox[8];
#pragma unroll
  for (int r = 0; r < 8; ++r) ox[r] = 0.0f;

  float* xa = xg0;  // write target this inner step
  float* xb = xg1;
  int epoch = 0;
  __syncthreads();

  for (int outer = 0; outer < MAX_OUTER; ++outer) {
    // ---- w-phase: w[i] = sum_k A[k][i]*(s[k]+b[k]-u[k]); s,u plain-read ----
    for (int k = tid; k < MDIM; k += TPB) rs[k] = sg[k] + bl[k] - ug[k];
    __syncthreads();
    {
      const int ii = tid & (NPER - 1);
      const int kg = tid >> 5;  // 0..7
      float pp = 0.0f;
#pragma unroll
      for (int kk = 0; kk < MDIM / 8; ++kk) {
        const int k = kg * (MDIM / 8) + kk;
        pp = fmaf(A[(size_t)k * NDIM + i0 + ii], rs[k], pp);
      }
      wred[ii][kg] = pp;
    }
    __syncthreads();
    if (tid < NPER) {
      float sum = 0.0f;
#pragma unroll
      for (int q = 0; q < 8; ++q) sum += wred[tid][q];
      wl[tid] = sum;
    }
    __syncthreads();

    // ---- inner loop: x <- max(x - eta*(c + rho*(Mx - w)), 0) ----
    for (int it = 0; it < X_INNER; ++it) {
      float acc[8];
#pragma unroll
      for (int r = 0; r < 8; ++r) acc[r] = 0.0f;
#pragma unroll
      for (int r = 0; r < 8; ++r) {
        const float4* Mr = Ml4[wave * 8 + r];
#pragma unroll
        for (int t = 0; t < 4; ++t) {
          const float4 m = Mr[64 * t + lane];
          acc[r] = fmaf(m.x, xr[t].x, acc[r]);
          acc[r] = fmaf(m.y, xr[t].y, acc[r]);
          acc[r] = fmaf(m.z, xr[t].z, acc[r]);
          acc[r] = fmaf(m.w, xr[t].w, acc[r]);
        }
      }
#pragma unroll
      for (int r = 0; r < 8; ++r) acc[r] = wave_reduce_sum(acc[r]);
#pragma unroll
      for (int r = 0; r < 8; ++r) {
        const int ii = wave * 8 + r;
        const float g = cl[ii] + RHO * (acc[r] - wl[ii]);
        ox[r] = fmaxf(ox[r] - XSTEP * g, 0.0f);
      }
      if (lane == 0) {  // plain 2x16B stores of the wave's 8 new x values
        float4* dst = (float4*)&xa[i0 + wave * 8];
        dst[0] = make_float4(ox[0], ox[1], ox[2], ox[3]);
        dst[1] = make_float4(ox[4], ox[5], ox[6], ox[7]);
      }
      ++epoch;
      grid_barrier(flags, epoch, bid);
      // restage full x: 4 plain float4 loads per lane (fresh from LLC)
      {
        const float4* src = (const float4*)xa;
#pragma unroll
        for (int t = 0; t < 4; ++t) xr[t] = src[64 * t + lane];
      }
      float* tmp = xa;
      xa = xb;
      xb = tmp;
    }

    // ---- Ax-phase: s,u update for OWN 16 k-rows only (64 KB A read) ----
#pragma unroll
    for (int r = 0; r < 4; ++r) {
      const int kk = wave * 4 + r;  // 0..15
      const int k = k0 + kk;
      const float4* Ar = (const float4*)(A + (size_t)k * NDIM);
      float pp = 0.0f;
#pragma unroll
      for (int t = 0; t < 4; ++t) {
        const float4 a = Ar[64 * t + lane];
        pp = fmaf(a.x, xr[t].x, pp);
        pp = fmaf(a.y, xr[t].y, pp);
        pp = fmaf(a.z, xr[t].z, pp);
        pp = fmaf(a.w, xr[t].w, pp);
      }
      pp = wave_reduce_sum(pp);
      if (lane == 0) {
        const float uk = uown[kk], bk = bl[k];
        const float sv = fmaxf(pp - bk + uk, 0.0f);
        const float uv = uk + pp - sv - bk;
        sown[kk] = sv;
        uown[kk] = uv;
        sg[k] = sv;  // plain stores; barrier's wbl2 publishes them
        ug[k] = uv;
      }
    }
    ++epoch;
    grid_barrier(flags, epoch, bid);
  }

  // ---- final outputs: [x | s | u | lambda | nu] as f32 ----
  if (wave == 0) {
#pragma unroll
    for (int t = 0; t < 4; ++t) ((float4*)out)[64 * t + lane] = xr[t];
  }
  if (tid < MPER) {
    const int k = k0 + tid;
    const float sv = sown[tid], uv = uown[tid];
    out[NDIM + k] = sv;
    out[NDIM + MDIM + k] = uv;
    out[NDIM + 2 * MDIM + k] = fmaxf(-RHO * uv, 0.0f);
  }
  // nu = max(c + A^T (rho*u), 0) for block's i-slice (full u, plain reads)
  for (int k = tid; k < MDIM; k += TPB) rs[k] = ug[k];
  __syncthreads();
  {
    const int ii = tid & (NPER - 1);
    const int kg = tid >> 5;
    float pp = 0.0f;
#pragma unroll
    for (int kk = 0; kk < MDIM / 8; ++kk) {
      const int k = kg * (MDIM / 8) + kk;
      pp = fmaf(A[(size_t)k * NDIM + i0 + ii], rs[k], pp);
    }
    wred[ii][kg] = pp;
  }
  __syncthreads();
  if (tid < NPER) {
    float t = 0.0f;
#pragma unroll
    for (int q = 0; q < 8; ++q) t += wred[tid][q];
    out[NDIM + 3 * MDIM + i0 + tid] = fmaxf(cl[tid] + RHO * t, 0.0f);
  }
}

// ---------------- host ----------------

extern "C" void kernel_launch(void* const* d_in, const int* in_sizes, int n_in,
                              void* d_out, int out_size, void* d_ws,
                              size_t ws_size, hipStream_t stream) {
  const float* A = (const float*)d_in[0];
  const float* b = (const float*)d_in[1];
  const float* c = (const float*)d_in[2];
  float* out = (float*)d_out;

  float* Mws = (float*)d_ws;               // 1024*1024 f32 = 4 MB
  float* xg0 = Mws + (size_t)NDIM * NDIM;  // 1024 (x ping buffer)
  float* xg1 = xg0 + NDIM;                 // 1024 (x pong buffer)
  float* sg = xg1 + NDIM;                  // 512
  float* ug = sg + MDIM;                   // 512
  int* flags = (int*)(ug + MDIM);          // GBLK*32 ints (128B apart)

  // zero s, u, flags (x buffers need no init: fully written before first
  // read). ws is poisoned 0xAA before every launch, so this runs every call.
  hipMemsetAsync(sg, 0, 2 * MDIM * sizeof(float) + GBLK * 32 * sizeof(int),
                 stream);

  dim3 g1(NDIM / ATA_BT, NDIM / ATA_BT);
  ata_kernel<<<g1, 256, 0, stream>>>(A, Mws);
  admm_kernel<<<GBLK, TPB, 0, stream>>>(A, b, c, Mws, xg0, xg1, sg, ug, flags,
                                        out);
}